// Round 7
// baseline (869.311 us; speedup 1.0000x reference)
//
#include <hip/hip_runtime.h>
#include <stdint.h>

#define D 1024
#define N 200000
#define C 50
#define B 4096
#define CLS 4
#define KParts 16
#define CAP 4096
#define NB3 ((N + 255) / 256)       // 782 blocks for the dots part
#define NWAVES ((N + 63) / 64)      // 3125 wave range slots

typedef float v2f __attribute__((ext_vector_type(2)));

// ws float offsets
static const size_t OFF_U     = 0;                           // C*N uints (ordering keys)
static const size_t OFF_TESQ  = (size_t)C * N;               // N floats
static const size_t OFF_GPART = OFF_TESQ + N;                // KParts*2500
static const size_t OFF_WPART = OFF_GPART + KParts * 2500;   // KParts*200
static const size_t OFF_RANGE = OFF_WPART + KParts * 200;    // NWAVES*2 uints
static const size_t OFF_SUMS  = OFF_RANGE + 6400;            // C floats
static const size_t OFF_CNT   = OFF_SUMS + C;                // 1 uint
static const size_t OFF_GR    = OFF_CNT + 1;                 // 2 uints: global ulo/uhi
static const size_t OFF_W8    = ((OFF_GR + 2 + 3) / 4) * 4;  // D*8 floats, 16B-aligned

__device__ __forceinline__ unsigned mapf(float v) {
    unsigned u = __float_as_uint(v);
    return (u & 0x80000000u) ? ~u : (u | 0x80000000u);
}
__device__ __forceinline__ float unmapf(unsigned u) {
    unsigned b = (u & 0x80000000u) ? (u ^ 0x80000000u) : ~u;
    return __uint_as_float(b);
}
// ordering key: tesq - 2*dot (monotone with dist2; csq constant per concept)
__device__ __forceinline__ unsigned keyu(float dot, float tesq) {
    return mapf(fmaf(-2.0f, dot, tesq));
}

// ---------------- KA: keys+tesq+per-wave range (782 blocks) fused with partial gram/wc (16) ----
__global__ __launch_bounds__(256) void kA_dots_gram(
    const float* __restrict__ concept, const float* __restrict__ te,
    const float* __restrict__ hxw, float* __restrict__ ws)
{
    int t = threadIdx.x;
    if (blockIdx.x < NB3) {
        int n = blockIdx.x * 256 + t;
        if (n >= N) return;   // whole-wave exits only; no barriers in this branch

        v2f acc[25];
        #pragma unroll
        for (int q = 0; q < 25; ++q) acc[q] = (v2f)(0.0f);
        float tesq = 0.f;

        const float* tp = te + n;
        for (int d0 = 0; d0 < D; d0 += 16) {
            float x[16];
            #pragma unroll
            for (int u = 0; u < 16; ++u)
                x[u] = tp[(size_t)(d0 + u) * N];
            #pragma unroll
            for (int u = 0; u < 16; ++u) {
                tesq = fmaf(x[u], x[u], tesq);
                const v2f* crow = (const v2f*)(concept + (d0 + u) * 50); // wave-uniform
                v2f xv; xv[0] = x[u]; xv[1] = x[u];
                #pragma unroll
                for (int q = 0; q < 25; ++q)
                    acc[q] = __builtin_elementwise_fma(xv, crow[q], acc[q]);
            }
        }

        unsigned* uws = (unsigned*)ws;
        unsigned umin = 0xFFFFFFFFu, umax = 0u;
        #pragma unroll
        for (int q = 0; q < 25; ++q) {
            unsigned u0 = keyu(acc[q][0], tesq);
            unsigned u1 = keyu(acc[q][1], tesq);
            uws[(size_t)(2 * q) * N + n]     = u0;
            uws[(size_t)(2 * q + 1) * N + n] = u1;
            umin = min(umin, min(u0, u1));
            umax = max(umax, max(u0, u1));
        }
        ws[OFF_TESQ + n] = tesq;

        #pragma unroll
        for (int off = 32; off > 0; off >>= 1) {
            umin = min(umin, (unsigned)__shfl_down((int)umin, off, 64));
            umax = max(umax, (unsigned)__shfl_down((int)umax, off, 64));
        }
        if ((t & 63) == 0) {
            int w = n >> 6;
            ((unsigned*)(ws + OFF_RANGE))[2 * w]     = umin;
            ((unsigned*)(ws + OFF_RANGE))[2 * w + 1] = umax;
        }
    } else {
        // ---- partial gram + partial wc over a 64-row d-slab ----
        __shared__ __align__(16) float ct[64 * 50];
        __shared__ float hs[4 * 64];
        int bid = blockIdx.x - NB3;
        int d0 = bid * 64;

        for (int i = t; i < 64 * 50; i += 256) ct[i] = concept[d0 * 50 + i];
        {
            int j = t >> 6, dd = t & 63;
            hs[t] = hxw[j * D + d0 + dd];
        }
        __syncthreads();

        float* gp = ws + OFF_GPART + (size_t)bid * 2500;
        for (int p = t; p < 2500; p += 256) {
            int i = p / 50, j = p - i * 50;
            float acc = 0.f;
            #pragma unroll 8
            for (int dd = 0; dd < 64; ++dd)
                acc = fmaf(ct[dd * 50 + i], ct[dd * 50 + j], acc);
            gp[p] = acc;
        }
        float* wp = ws + OFF_WPART + (size_t)bid * 200;
        if (t < 200) {
            int j = t / 50, c = t - j * 50;
            float acc = 0.f;
            #pragma unroll 8
            for (int dd = 0; dd < 64; ++dd)
                acc = fmaf(hs[j * 64 + dd], ct[dd * 50 + c], acc);
            wp[t] = acc;
        }
    }
}

// ---------------- K1b: single-wave — reduce partials+range, metrics, GJ solve, W8 ----------
// 64-thread block: __syncthreads compiles to waitcnt only (no s_barrier) -> GJ is cheap.
__global__ __launch_bounds__(64) void k1b_solve(
    const float* __restrict__ concept, const float* __restrict__ hxw,
    float* __restrict__ ws, float* __restrict__ out)
{
    __shared__ float gsh[2500];
    __shared__ float A[50 * 56];     // [G | wc^T | pad]
    __shared__ float colp[C];
    int t = threadIdx.x;

    if (t == 0) ((unsigned*)(ws + OFF_CNT))[0] = 0u;   // k4 completion counter

    // global key range from wave slots
    {
        const unsigned* rg = (const unsigned*)(ws + OFF_RANGE);
        unsigned mn = 0xFFFFFFFFu, mx = 0u;
        for (int i = t; i < NWAVES; i += 64) {
            mn = min(mn, rg[2 * i]);
            mx = max(mx, rg[2 * i + 1]);
        }
        #pragma unroll
        for (int off = 32; off > 0; off >>= 1) {
            mn = min(mn, (unsigned)__shfl_down((int)mn, off, 64));
            mx = max(mx, (unsigned)__shfl_down((int)mx, off, 64));
        }
        if (t == 0) {
            ((unsigned*)(ws + OFF_GR))[0] = mn;
            ((unsigned*)(ws + OFF_GR))[1] = mx;
        }
    }

    // sum gram partials (float4 along p), metrics
    float s_all = 0.f, s_tr = 0.f, s_abs = 0.f;
    for (int p4 = t * 4; p4 < 2500; p4 += 256) {
        float4 g = {0.f, 0.f, 0.f, 0.f};
        #pragma unroll
        for (int b = 0; b < KParts; ++b) {
            float4 v = *(const float4*)(ws + OFF_GPART + (size_t)b * 2500 + p4);
            g.x += v.x; g.y += v.y; g.z += v.z; g.w += v.w;
        }
        *(float4*)(gsh + p4) = g;
        float gg[4] = {g.x, g.y, g.z, g.w};
        #pragma unroll
        for (int e = 0; e < 4; ++e) {
            int p = p4 + e;
            int i = p / 50, j = p - i * 50;
            float e_ = (i == j) ? 1.0f : 0.0f;
            s_all += gg[e];
            if (i == j) s_tr += gg[e];
            s_abs += fabsf(gg[e] - e_);
        }
    }
    #pragma unroll
    for (int off = 32; off > 0; off >>= 1) {
        s_all += __shfl_down(s_all, off, 64);
        s_tr  += __shfl_down(s_tr,  off, 64);
        s_abs += __shfl_down(s_abs, off, 64);
    }
    if (t == 0) {
        out[32769] = (s_all - s_tr) / 2500.0f;  // L_sparse_2
        out[32770] = s_tr / 2500.0f;            // norm_metrics
        out[32771] = s_abs / 2500.0f;           // similarity_penalty
    }
    __syncthreads();

    // build augmented [G | wc^T]
    for (int p = t; p < 50 * 56; p += 64) {
        int r = p / 56, col = p - r * 56;
        float v = 0.f;
        if (col < 50) v = gsh[r * 50 + col];
        else if (col < 54) {
            float w = 0.f;
            #pragma unroll
            for (int b = 0; b < KParts; ++b)
                w += ws[OFF_WPART + (size_t)b * 200 + (col - 50) * 50 + r];
            v = w;
        }
        A[p] = v;
    }
    __syncthreads();

    // pivotless Gauss-Jordan (G is SPD -> stable); 1-wave so barriers are waitcnt-only
    for (int pc = 0; pc < C; ++pc) {
        if (t < C) colp[t] = A[t * 56 + pc];
        __syncthreads();
        float pinv = 1.0f / colp[pc];
        if (t < 56) A[pc * 56 + t] *= pinv;
        __syncthreads();
        for (int p = t; p < 50 * 56; p += 64) {
            int r = p / 56, col = p - r * 56;
            if (r != pc) A[p] = fmaf(-colp[r], A[pc * 56 + col], A[p]);
        }
        __syncthreads();
    }

    // W8[d][0..3] = hxw[j][d]; W8[d][4..7] = sum_c concept[d][c] * A[c][50+j]
    for (int d = t; d < D; d += 64) {
        float wy0 = 0.f, wy1 = 0.f, wy2 = 0.f, wy3 = 0.f;
        for (int c = 0; c < C; ++c) {
            float cv = concept[d * 50 + c];
            wy0 = fmaf(cv, A[c * 56 + 50], wy0);
            wy1 = fmaf(cv, A[c * 56 + 51], wy1);
            wy2 = fmaf(cv, A[c * 56 + 52], wy2);
            wy3 = fmaf(cv, A[c * 56 + 53], wy3);
        }
        float4 lo, hi;
        lo.x = hxw[0 * D + d]; lo.y = hxw[1 * D + d];
        lo.z = hxw[2 * D + d]; lo.w = hxw[3 * D + d];
        hi.x = wy0; hi.y = wy1; hi.z = wy2; hi.w = wy3;
        *(float4*)(ws + OFF_W8 + (size_t)d * 8)     = lo;
        *(float4*)(ws + OFF_W8 + (size_t)d * 8 + 4) = hi;
    }
}

// ---------------- K4+pred merged: blocks 0..C-1 select; blocks C.. do predictions ----------
#define PRED_BLOCKS (B / 16)    // 256 blocks, 16 rows each (1 row per wave)
__global__ __launch_bounds__(1024) void k4_sel_pred(
    const float* __restrict__ ws, float* __restrict__ wsw,
    const float* __restrict__ X, const float* __restrict__ hxb,
    float* __restrict__ out, const int* __restrict__ topk)
{
    int t = threadIdx.x;
    int lane = t & 63, wid = t >> 6;

    if (blockIdx.x >= C) {
        // ---- prediction part: [orig_pred | y_pred] = X @ W8 + bias, 1 row per wave ----
        int r = (blockIdx.x - C) * 16 + wid;
        const float* xr = X + (size_t)r * D;
        const float* w8 = ws + OFF_W8;

        float acc[8];
        #pragma unroll
        for (int j = 0; j < 8; ++j) acc[j] = 0.f;
        #pragma unroll
        for (int i = 0; i < 16; ++i) {
            int d = i * 64 + lane;
            float x = xr[d];
            float4 lo = *(const float4*)(w8 + (size_t)d * 8);
            float4 hi = *(const float4*)(w8 + (size_t)d * 8 + 4);
            acc[0] = fmaf(x, lo.x, acc[0]);
            acc[1] = fmaf(x, lo.y, acc[1]);
            acc[2] = fmaf(x, lo.z, acc[2]);
            acc[3] = fmaf(x, lo.w, acc[3]);
            acc[4] = fmaf(x, hi.x, acc[4]);
            acc[5] = fmaf(x, hi.y, acc[5]);
            acc[6] = fmaf(x, hi.z, acc[6]);
            acc[7] = fmaf(x, hi.w, acc[7]);
        }
        #pragma unroll
        for (int j = 0; j < 8; ++j) {
            float v = acc[j];
            #pragma unroll
            for (int off = 32; off > 0; off >>= 1) v += __shfl_down(v, off, 64);
            if (lane == 0) {
                float b = hxb[j & 3];
                if (j < 4) out[(size_t)r * CLS + j] = v + b;
                else       out[16384 + (size_t)r * CLS + (j - 4)] = v + b;
            }
        }
        return;
    }

    // ---- top-k select part ----
    int c = blockIdx.x;
    const unsigned* uarr = (const unsigned*)ws + (size_t)c * N;
    const float* tesq = ws + OFF_TESQ;

    __shared__ unsigned hist[4096];
    __shared__ unsigned wsum[16], woff[16];
    __shared__ unsigned sh_bin; __shared__ int sh_rem;
    __shared__ int cnt;
    __shared__ unsigned cand_u[CAP];
    __shared__ int      cand_i[CAP];
    __shared__ float fred[16];

    unsigned ulo = ((const unsigned*)(ws + OFF_GR))[0];
    unsigned uhi = ((const unsigned*)(ws + OFF_GR))[1];
    int rem = *topk;
    unsigned long long width = (unsigned long long)(uhi - ulo) + 1ull;

    // ---- pass 1: histogram over 4096 linear bins of the global range ----
    for (int i = t; i < 4096; i += 1024) hist[i] = 0u;
    __syncthreads();
    for (int n = t; n < N; n += 1024) {
        unsigned u = uarr[n];
        unsigned bin = (unsigned)(((unsigned long long)(u - ulo) * 4096ull) / width);
        atomicAdd(&hist[bin], 1u);
    }
    __syncthreads();
    {
        unsigned b0 = (unsigned)t * 4u;
        unsigned h0 = hist[b0], h1 = hist[b0 + 1], h2 = hist[b0 + 2], h3 = hist[b0 + 3];
        unsigned s4 = h0 + h1 + h2 + h3;
        unsigned x = s4;
        #pragma unroll
        for (int off = 1; off < 64; off <<= 1) {
            unsigned y = (unsigned)__shfl_up((int)x, off, 64);
            if (lane >= off) x += y;
        }
        if (lane == 63) wsum[wid] = x;
        __syncthreads();
        if (t == 0) {
            unsigned run = 0;
            for (int w = 0; w < 16; ++w) { woff[w] = run; run += wsum[w]; }
        }
        __syncthreads();
        unsigned cumBefore = woff[wid] + x - s4;
        unsigned remu = (unsigned)rem;
        if (cumBefore < remu && remu <= cumBefore + s4) {
            unsigned cum = cumBefore, bin = b0, r2 = 1;
            unsigned hh[4] = {h0, h1, h2, h3};
            #pragma unroll
            for (int j = 0; j < 4; ++j) {
                if (cum + hh[j] >= remu) { bin = b0 + j; r2 = remu - cum; break; }
                cum += hh[j];
            }
            sh_bin = bin; sh_rem = (int)r2;
        }
        __syncthreads();
        unsigned b = sh_bin;
        rem = sh_rem;
        unsigned base = ((const unsigned*)(ws + OFF_GR))[0];
        ulo = base + (unsigned)(((unsigned long long)b * width + 4095ull) / 4096ull);
        uhi = base + (unsigned)((((unsigned long long)(b + 1) * width + 4095ull) / 4096ull) - 1ull);
        __syncthreads();
    }

    // ---- final: sum recovered dots below cutoff bin; collect cutoff-bin candidates ----
    if (t == 0) cnt = 0;
    __syncthreads();
    float lsum = 0.f;
    for (int n = t; n < N; n += 1024) {
        unsigned u = uarr[n];
        if (u < ulo) {
            lsum += 0.5f * (tesq[n] - unmapf(u));   // dot = (tesq - key)/2
        } else if (u <= uhi) {
            int s = atomicAdd(&cnt, 1);
            if (s < CAP) { cand_u[s] = u; cand_i[s] = n; }
        }
    }
    __syncthreads();
    int cc = cnt < CAP ? cnt : CAP;
    for (int ci = t; ci < cc; ci += 1024) {
        unsigned ui = cand_u[ci]; int ii = cand_i[ci];
        int rank = 0;
        for (int j = 0; j < cc; ++j) {
            unsigned uj = cand_u[j];
            rank += (uj < ui || (uj == ui && cand_i[j] < ii)) ? 1 : 0;
        }
        if (rank < rem) lsum += 0.5f * (tesq[ii] - unmapf(ui));
    }
    #pragma unroll
    for (int off = 32; off > 0; off >>= 1) lsum += __shfl_down(lsum, off, 64);
    if (lane == 0) fred[wid] = lsum;
    __syncthreads();
    if (t == 0) {
        float tot = 0.f;
        for (int w = 0; w < 16; ++w) tot += fred[w];
        wsw[OFF_SUMS + c] = tot;
        __threadfence();
        unsigned done = atomicAdd((unsigned*)(wsw + OFF_CNT), 1u);
        if (done == C - 1) {
            float s = 0.f;
            for (int i = 0; i < C; ++i) s += atomicAdd(&wsw[OFF_SUMS + i], 0.0f);
            out[32768] = s / (float)((*topk) * C);
        }
    }
}

extern "C" void kernel_launch(void* const* d_in, const int* in_sizes, int n_in,
                              void* d_out, int out_size, void* d_ws, size_t ws_size,
                              hipStream_t stream) {
    (void)in_sizes; (void)n_in; (void)out_size; (void)ws_size;
    const float* concept = (const float*)d_in[0];
    const float* te      = (const float*)d_in[1];
    const float* X       = (const float*)d_in[2];
    const float* hxw     = (const float*)d_in[3];
    const float* hxb     = (const float*)d_in[4];
    const int*   topk    = (const int*)d_in[5];
    float* out = (float*)d_out;
    float* ws  = (float*)d_ws;

    kA_dots_gram<<<dim3(NB3 + KParts), dim3(256), 0, stream>>>(concept, te, hxw, ws);
    k1b_solve<<<dim3(1), dim3(64), 0, stream>>>(concept, hxw, ws, out);
    k4_sel_pred<<<dim3(C + PRED_BLOCKS), dim3(1024), 0, stream>>>(ws, ws, X, hxb, out, topk);
}

// Round 8
// 695.977 us; speedup vs baseline: 1.2491x; 1.2491x over previous
//
#include <hip/hip_runtime.h>
#include <stdint.h>

#define D 1024
#define N 200000
#define C 50
#define B 4096
#define CLS 4
#define KParts 16
#define CAP 4096
#define NB3 ((N + 255) / 256)       // 782 blocks for the dots part
#define NWAVES ((N + 63) / 64)      // 3125 wave range slots

typedef float v2f __attribute__((ext_vector_type(2)));

// ws float offsets
static const size_t OFF_U     = 0;                           // C*N uints (ordering keys)
static const size_t OFF_TESQ  = (size_t)C * N;               // N floats
static const size_t OFF_GPART = OFF_TESQ + N;                // KParts*2500
static const size_t OFF_WPART = OFF_GPART + KParts * 2500;   // KParts*200
static const size_t OFF_RANGE = OFF_WPART + KParts * 200;    // NWAVES*2 uints
static const size_t OFF_SUMS  = OFF_RANGE + 6400;            // C floats
static const size_t OFF_CNT   = OFF_SUMS + C;                // 1 uint
static const size_t OFF_GR    = OFF_CNT + 1;                 // 2 uints: global ulo/uhi
static const size_t OFF_W8    = ((OFF_GR + 2 + 3) / 4) * 4;  // D*8 floats, 16B-aligned

__device__ __forceinline__ unsigned mapf(float v) {
    unsigned u = __float_as_uint(v);
    return (u & 0x80000000u) ? ~u : (u | 0x80000000u);
}
__device__ __forceinline__ float unmapf(unsigned u) {
    unsigned b = (u & 0x80000000u) ? (u ^ 0x80000000u) : ~u;
    return __uint_as_float(b);
}
// ordering key: tesq - 2*dot (monotone with dist2; csq constant per concept)
__device__ __forceinline__ unsigned keyu(float dot, float tesq) {
    return mapf(fmaf(-2.0f, dot, tesq));
}

// ---------------- KA: keys+tesq+per-wave range (782 blocks) fused with partial gram/wc (16) ----
__global__ __launch_bounds__(256) void kA_dots_gram(
    const float* __restrict__ concept, const float* __restrict__ te,
    const float* __restrict__ hxw, float* __restrict__ ws)
{
    int t = threadIdx.x;
    if (blockIdx.x < NB3) {
        int n = blockIdx.x * 256 + t;
        if (n >= N) return;   // whole-wave exits only; no barriers in this branch

        v2f acc[25];
        #pragma unroll
        for (int q = 0; q < 25; ++q) acc[q] = (v2f)(0.0f);
        float tesq = 0.f;

        const float* tp = te + n;
        for (int d0 = 0; d0 < D; d0 += 16) {
            float x[16];
            #pragma unroll
            for (int u = 0; u < 16; ++u)
                x[u] = tp[(size_t)(d0 + u) * N];
            #pragma unroll
            for (int u = 0; u < 16; ++u) {
                tesq = fmaf(x[u], x[u], tesq);
                const v2f* crow = (const v2f*)(concept + (d0 + u) * 50); // wave-uniform
                v2f xv; xv[0] = x[u]; xv[1] = x[u];
                #pragma unroll
                for (int q = 0; q < 25; ++q)
                    acc[q] = __builtin_elementwise_fma(xv, crow[q], acc[q]);
            }
        }

        unsigned* uws = (unsigned*)ws;
        unsigned umin = 0xFFFFFFFFu, umax = 0u;
        #pragma unroll
        for (int q = 0; q < 25; ++q) {
            unsigned u0 = keyu(acc[q][0], tesq);
            unsigned u1 = keyu(acc[q][1], tesq);
            uws[(size_t)(2 * q) * N + n]     = u0;
            uws[(size_t)(2 * q + 1) * N + n] = u1;
            umin = min(umin, min(u0, u1));
            umax = max(umax, max(u0, u1));
        }
        ws[OFF_TESQ + n] = tesq;

        #pragma unroll
        for (int off = 32; off > 0; off >>= 1) {
            umin = min(umin, (unsigned)__shfl_down((int)umin, off, 64));
            umax = max(umax, (unsigned)__shfl_down((int)umax, off, 64));
        }
        if ((t & 63) == 0) {
            int w = n >> 6;
            ((unsigned*)(ws + OFF_RANGE))[2 * w]     = umin;
            ((unsigned*)(ws + OFF_RANGE))[2 * w + 1] = umax;
        }
    } else {
        // ---- partial gram + partial wc over a 64-row d-slab ----
        __shared__ __align__(16) float ct[64 * 50];
        __shared__ float hs[4 * 64];
        int bid = blockIdx.x - NB3;
        int d0 = bid * 64;

        for (int i = t; i < 64 * 50; i += 256) ct[i] = concept[d0 * 50 + i];
        {
            int j = t >> 6, dd = t & 63;
            hs[t] = hxw[j * D + d0 + dd];
        }
        __syncthreads();

        float* gp = ws + OFF_GPART + (size_t)bid * 2500;
        for (int p = t; p < 2500; p += 256) {
            int i = p / 50, j = p - i * 50;
            float acc = 0.f;
            #pragma unroll 8
            for (int dd = 0; dd < 64; ++dd)
                acc = fmaf(ct[dd * 50 + i], ct[dd * 50 + j], acc);
            gp[p] = acc;
        }
        float* wp = ws + OFF_WPART + (size_t)bid * 200;
        if (t < 200) {
            int j = t / 50, c = t - j * 50;
            float acc = 0.f;
            #pragma unroll 8
            for (int dd = 0; dd < 64; ++dd)
                acc = fmaf(hs[j * 64 + dd], ct[dd * 50 + c], acc);
            wp[t] = acc;
        }
    }
}

// ---------------- K1b: reduce partials+range, metrics, solve [G|wc^T], W8 ----------
__global__ __launch_bounds__(256) void k1b_solve(
    const float* __restrict__ concept, const float* __restrict__ hxw,
    float* __restrict__ ws, float* __restrict__ out)
{
    __shared__ float gsh[2500];
    __shared__ float A[50 * 56];     // [G | wc^T | pad]
    __shared__ float colp[C];
    __shared__ float part[3][4];
    __shared__ unsigned ured[2][4];
    int t = threadIdx.x;
    int lane = t & 63, wid = t >> 6;

    if (t == 0) ((unsigned*)(ws + OFF_CNT))[0] = 0u;   // k4 completion counter

    // global key range from wave slots
    {
        const unsigned* rg = (const unsigned*)(ws + OFF_RANGE);
        unsigned mn = 0xFFFFFFFFu, mx = 0u;
        for (int i = t; i < NWAVES; i += 256) {
            mn = min(mn, rg[2 * i]);
            mx = max(mx, rg[2 * i + 1]);
        }
        #pragma unroll
        for (int off = 32; off > 0; off >>= 1) {
            mn = min(mn, (unsigned)__shfl_down((int)mn, off, 64));
            mx = max(mx, (unsigned)__shfl_down((int)mx, off, 64));
        }
        if (lane == 0) { ured[0][wid] = mn; ured[1][wid] = mx; }
    }

    float s_all = 0.f, s_tr = 0.f, s_abs = 0.f;
    for (int p = t; p < 2500; p += 256) {
        float g = 0.f;
        #pragma unroll
        for (int b = 0; b < KParts; ++b)
            g += ws[OFF_GPART + (size_t)b * 2500 + p];
        gsh[p] = g;
        int i = p / 50, j = p - i * 50;
        float e = (i == j) ? 1.0f : 0.0f;
        s_all += g;
        if (i == j) s_tr += g;
        s_abs += fabsf(g - e);
    }
    #pragma unroll
    for (int off = 32; off > 0; off >>= 1) {
        s_all += __shfl_down(s_all, off, 64);
        s_tr  += __shfl_down(s_tr,  off, 64);
        s_abs += __shfl_down(s_abs, off, 64);
    }
    if (lane == 0) { part[0][wid] = s_all; part[1][wid] = s_tr; part[2][wid] = s_abs; }
    __syncthreads();
    if (t == 0) {
        float a  = part[0][0] + part[0][1] + part[0][2] + part[0][3];
        float tr = part[1][0] + part[1][1] + part[1][2] + part[1][3];
        float ab = part[2][0] + part[2][1] + part[2][2] + part[2][3];
        out[32769] = (a - tr) / 2500.0f;   // L_sparse_2
        out[32770] = tr / 2500.0f;         // norm_metrics
        out[32771] = ab / 2500.0f;         // similarity_penalty
        unsigned mn = min(min(ured[0][0], ured[0][1]), min(ured[0][2], ured[0][3]));
        unsigned mx = max(max(ured[1][0], ured[1][1]), max(ured[1][2], ured[1][3]));
        ((unsigned*)(ws + OFF_GR))[0] = mn;
        ((unsigned*)(ws + OFF_GR))[1] = mx;
    }

    for (int p = t; p < 50 * 56; p += 256) {
        int r = p / 56, col = p - r * 56;
        float v = 0.f;
        if (col < 50) v = gsh[r * 50 + col];
        else if (col < 54) {
            float w = 0.f;
            #pragma unroll
            for (int b = 0; b < KParts; ++b)
                w += ws[OFF_WPART + (size_t)b * 200 + (col - 50) * 50 + r];
            v = w;
        }
        A[p] = v;
    }
    __syncthreads();

    // pivotless Gauss-Jordan (G is SPD -> stable without pivoting)
    for (int pc = 0; pc < C; ++pc) {
        if (t < C) colp[t] = A[t * 56 + pc];
        __syncthreads();
        float pinv = 1.0f / colp[pc];
        if (t < 56) A[pc * 56 + t] *= pinv;
        __syncthreads();
        for (int p = t; p < 50 * 56; p += 256) {
            int r = p / 56, col = p - r * 56;
            if (r != pc) A[p] = fmaf(-colp[r], A[pc * 56 + col], A[p]);
        }
        __syncthreads();
    }

    // W8[d][0..3] = hxw[j][d]; W8[d][4..7] = sum_c concept[d][c] * A[c][50+j]
    for (int d = t; d < D; d += 256) {
        float wy0 = 0.f, wy1 = 0.f, wy2 = 0.f, wy3 = 0.f;
        for (int c = 0; c < C; ++c) {
            float cv = concept[d * 50 + c];
            wy0 = fmaf(cv, A[c * 56 + 50], wy0);
            wy1 = fmaf(cv, A[c * 56 + 51], wy1);
            wy2 = fmaf(cv, A[c * 56 + 52], wy2);
            wy3 = fmaf(cv, A[c * 56 + 53], wy3);
        }
        float4 lo, hi;
        lo.x = hxw[0 * D + d]; lo.y = hxw[1 * D + d];
        lo.z = hxw[2 * D + d]; lo.w = hxw[3 * D + d];
        hi.x = wy0; hi.y = wy1; hi.z = wy2; hi.w = wy3;
        *(float4*)(ws + OFF_W8 + (size_t)d * 8)     = lo;
        *(float4*)(ws + OFF_W8 + (size_t)d * 8 + 4) = hi;
    }
}

// ---------------- Kpred: [orig_pred | y_pred] = X @ W8 + bias -----------------
__global__ __launch_bounds__(256) void kpred(
    const float* __restrict__ X, const float* __restrict__ hxb,
    const float* __restrict__ ws, float* __restrict__ out)
{
    int t = threadIdx.x;
    int lane = t & 63, w = t >> 6;
    int r = blockIdx.x * 4 + w;
    const float* xr = X + (size_t)r * D;
    const float* w8 = ws + OFF_W8;

    float acc[8];
    #pragma unroll
    for (int j = 0; j < 8; ++j) acc[j] = 0.f;
    #pragma unroll
    for (int i = 0; i < 16; ++i) {
        int d = i * 64 + lane;
        float x = xr[d];
        float4 lo = *(const float4*)(w8 + (size_t)d * 8);
        float4 hi = *(const float4*)(w8 + (size_t)d * 8 + 4);
        acc[0] = fmaf(x, lo.x, acc[0]);
        acc[1] = fmaf(x, lo.y, acc[1]);
        acc[2] = fmaf(x, lo.z, acc[2]);
        acc[3] = fmaf(x, lo.w, acc[3]);
        acc[4] = fmaf(x, hi.x, acc[4]);
        acc[5] = fmaf(x, hi.y, acc[5]);
        acc[6] = fmaf(x, hi.z, acc[6]);
        acc[7] = fmaf(x, hi.w, acc[7]);
    }
    #pragma unroll
    for (int j = 0; j < 8; ++j) {
        float v = acc[j];
        #pragma unroll
        for (int off = 32; off > 0; off >>= 1) v += __shfl_down(v, off, 64);
        if (lane == 0) {
            float b = hxb[j & 3];
            if (j < 4) out[(size_t)r * CLS + j] = v + b;
            else       out[16384 + (size_t)r * CLS + (j - 4)] = v + b;
        }
    }
}

// ---------------- K4: top-k from u keys (1 histogram + 1 final pass) + fused L_sparse_1 ------
__global__ __launch_bounds__(1024) void k4_select(
    const float* __restrict__ ws, float* __restrict__ wsw,
    float* __restrict__ out, const int* __restrict__ topk)
{
    int c = blockIdx.x, t = threadIdx.x;
    int lane = t & 63, wid = t >> 6;
    const unsigned* uarr = (const unsigned*)ws + (size_t)c * N;
    const float* tesq = ws + OFF_TESQ;

    __shared__ unsigned hist[4096];
    __shared__ unsigned wsum[16], woff[16];
    __shared__ unsigned sh_bin; __shared__ int sh_rem;
    __shared__ int cnt;
    __shared__ unsigned cand_u[CAP];
    __shared__ int      cand_i[CAP];
    __shared__ float fred[16];

    unsigned ulo = ((const unsigned*)(ws + OFF_GR))[0];
    unsigned uhi = ((const unsigned*)(ws + OFF_GR))[1];
    int rem = *topk;
    unsigned long long width = (unsigned long long)(uhi - ulo) + 1ull;

    // ---- pass 1: histogram over 4096 linear bins of the global range ----
    for (int i = t; i < 4096; i += 1024) hist[i] = 0u;
    __syncthreads();
    for (int n = t; n < N; n += 1024) {
        unsigned u = uarr[n];
        unsigned bin = (unsigned)(((unsigned long long)(u - ulo) * 4096ull) / width);
        atomicAdd(&hist[bin], 1u);
    }
    __syncthreads();
    {
        unsigned b0 = (unsigned)t * 4u;
        unsigned h0 = hist[b0], h1 = hist[b0 + 1], h2 = hist[b0 + 2], h3 = hist[b0 + 3];
        unsigned s4 = h0 + h1 + h2 + h3;
        unsigned x = s4;
        #pragma unroll
        for (int off = 1; off < 64; off <<= 1) {
            unsigned y = (unsigned)__shfl_up((int)x, off, 64);
            if (lane >= off) x += y;
        }
        if (lane == 63) wsum[wid] = x;
        __syncthreads();
        if (t == 0) {
            unsigned run = 0;
            for (int w = 0; w < 16; ++w) { woff[w] = run; run += wsum[w]; }
        }
        __syncthreads();
        unsigned cumBefore = woff[wid] + x - s4;
        unsigned remu = (unsigned)rem;
        if (cumBefore < remu && remu <= cumBefore + s4) {
            unsigned cum = cumBefore, bin = b0, r2 = 1;
            unsigned hh[4] = {h0, h1, h2, h3};
            #pragma unroll
            for (int j = 0; j < 4; ++j) {
                if (cum + hh[j] >= remu) { bin = b0 + j; r2 = remu - cum; break; }
                cum += hh[j];
            }
            sh_bin = bin; sh_rem = (int)r2;
        }
        __syncthreads();
        unsigned b = sh_bin;
        rem = sh_rem;
        ulo = ((const unsigned*)(ws + OFF_GR))[0]
              + (unsigned)(((unsigned long long)b * width + 4095ull) / 4096ull);
        uhi = ((const unsigned*)(ws + OFF_GR))[0]
              + (unsigned)((((unsigned long long)(b + 1) * width + 4095ull) / 4096ull) - 1ull);
        __syncthreads();
    }

    // ---- final: sum recovered dots below cutoff bin; collect cutoff-bin candidates ----
    if (t == 0) cnt = 0;
    __syncthreads();
    float lsum = 0.f;
    for (int n = t; n < N; n += 1024) {
        unsigned u = uarr[n];
        if (u < ulo) {
            lsum += 0.5f * (tesq[n] - unmapf(u));   // dot = (tesq - key)/2
        } else if (u <= uhi) {
            int s = atomicAdd(&cnt, 1);
            if (s < CAP) { cand_u[s] = u; cand_i[s] = n; }
        }
    }
    __syncthreads();
    int cc = cnt < CAP ? cnt : CAP;
    for (int ci = t; ci < cc; ci += 1024) {
        unsigned ui = cand_u[ci]; int ii = cand_i[ci];
        int rank = 0;
        for (int j = 0; j < cc; ++j) {
            unsigned uj = cand_u[j];
            rank += (uj < ui || (uj == ui && cand_i[j] < ii)) ? 1 : 0;
        }
        if (rank < rem) lsum += 0.5f * (tesq[ii] - unmapf(ui));
    }
    #pragma unroll
    for (int off = 32; off > 0; off >>= 1) lsum += __shfl_down(lsum, off, 64);
    if (lane == 0) fred[wid] = lsum;
    __syncthreads();
    if (t == 0) {
        float tot = 0.f;
        for (int w = 0; w < 16; ++w) tot += fred[w];
        wsw[OFF_SUMS + c] = tot;
        __threadfence();
        unsigned done = atomicAdd((unsigned*)(wsw + OFF_CNT), 1u);
        if (done == C - 1) {
            float s = 0.f;
            for (int i = 0; i < C; ++i) s += atomicAdd(&wsw[OFF_SUMS + i], 0.0f);
            out[32768] = s / (float)((*topk) * C);
        }
    }
}

extern "C" void kernel_launch(void* const* d_in, const int* in_sizes, int n_in,
                              void* d_out, int out_size, void* d_ws, size_t ws_size,
                              hipStream_t stream) {
    (void)in_sizes; (void)n_in; (void)out_size; (void)ws_size;
    const float* concept = (const float*)d_in[0];
    const float* te      = (const float*)d_in[1];
    const float* X       = (const float*)d_in[2];
    const float* hxw     = (const float*)d_in[3];
    const float* hxb     = (const float*)d_in[4];
    const int*   topk    = (const int*)d_in[5];
    float* out = (float*)d_out;
    float* ws  = (float*)d_ws;

    kA_dots_gram<<<dim3(NB3 + KParts), dim3(256), 0, stream>>>(concept, te, hxw, ws);
    k1b_solve<<<dim3(1), dim3(256), 0, stream>>>(concept, hxw, ws, out);
    kpred<<<dim3(B / 4), dim3(256), 0, stream>>>(X, hxb, ws, out);
    k4_select<<<dim3(C), dim3(1024), 0, stream>>>(ws, ws, out, topk);
}